// Round 9
// baseline (141.998 us; speedup 1.0000x reference)
//
#include <hip/hip_runtime.h>

#define N_NODES_C 50000
#define F_IN_C 64
#define HID_C 128
#define N_GRAPHS_C 500
#define N_CLS_C 10
#define MLP_HID_C 50
#define SCAN_TILE 1024
#define N_SCAN_BLK ((N_NODES_C + SCAN_TILE - 1) / SCAN_TILE)   // 49
#define N_TILES (N_NODES_C / 16)                               // 3125
#define N_RANGES 8
#define RANGE_SZ ((N_NODES_C + N_RANGES - 1) / N_RANGES)       // 6250

using short8 = __attribute__((ext_vector_type(8))) short;
using f32x4  = __attribute__((ext_vector_type(4))) float;

__device__ __forceinline__ int bl_i(int v, int l) {
    return __builtin_amdgcn_readlane(v, l);
}
__device__ __forceinline__ float uf(unsigned u) { return __uint_as_float(u); }

// round-to-nearest-even bf16 pack of two floats -> (lo=a, hi=b)
__device__ __forceinline__ unsigned pk_bf16(float a, float b) {
    unsigned ua = __float_as_uint(a), ub = __float_as_uint(b);
    ua += 0x7FFFu + ((ua >> 16) & 1u);
    ub += 0x7FFFu + ((ub >> 16) & 1u);
    return (ua >> 16) | (ub & 0xFFFF0000u);
}

union U8 { unsigned u[4]; uint4 q; short8 s; };

// ---------------------------------------------------------------------------
// Stage 1: XCD-range-partitioned degree histogram (group g = blockIdx&7 only
// counts dst in its range -> deg_i lines stay in one XCD's L2, no cross-XCD
// atomic ping-pong) + bf16-compress x + graph bounds. dst is re-read 8x
// (streaming, cheap).
// ---------------------------------------------------------------------------
__global__ __launch_bounds__(256) void hist_kernel(
    const int* __restrict__ dst,
    const int* __restrict__ batch,
    const float* __restrict__ x,
    int* __restrict__ deg_i,
    unsigned* __restrict__ xh,
    int* __restrict__ start,
    int n_edges)
{
    int g = blockIdx.x & 7;
    int lo = g * RANGE_SZ;
    for (int e = (blockIdx.x >> 3) * 256 + threadIdx.x; e < n_edges; e += 65536) {
        int d = dst[e];
        if ((unsigned)(d - lo) < (unsigned)RANGE_SZ)
            atomicAdd(&deg_i[d], 1);
    }

    int tid = blockIdx.x * 256 + threadIdx.x;
    int stride = gridDim.x * 256;
    const float2* xf2 = (const float2*)x;
    int nx = N_NODES_C * (F_IN_C / 2);
    for (int i = tid; i < nx; i += stride) {
        float2 v = xf2[i];
        xh[i] = pk_bf16(v.x, v.y);
    }

    for (int i = tid; i < N_NODES_C; i += stride) {
        int b = batch[i];
        if (i == 0) { for (int gg = 0; gg <= b; ++gg) start[gg] = 0; }
        else { int p = batch[i - 1]; for (int gg = p + 1; gg <= b; ++gg) start[gg] = i; }
        if (i == N_NODES_C - 1) { for (int gg = b + 1; gg <= N_GRAPHS_C; ++gg) start[gg] = N_NODES_C; }
    }
}

// Stage 2a: per-1024-tile sums
__global__ __launch_bounds__(256) void scan1_kernel(
    const int* __restrict__ deg_i, int* __restrict__ bsums, int n)
{
    __shared__ int s[256];
    int base = blockIdx.x * SCAN_TILE;
    int t = threadIdx.x;
    int sum = 0;
    #pragma unroll
    for (int j = 0; j < 4; ++j) {
        int i = base + t * 4 + j;
        sum += (i < n) ? deg_i[i] : 0;
    }
    s[t] = sum;
    __syncthreads();
    for (int off = 128; off > 0; off >>= 1) {
        if (t < off) s[t] += s[t + off];
        __syncthreads();
    }
    if (t == 0) bsums[blockIdx.x] = s[0];
}

// Stage 2b: tile-prefix via wave-reduce of bsums + intra-tile exclusive scan.
// Writes off[] and cursor[] (scatter's atomic base).
__global__ __launch_bounds__(256) void scan3_kernel(
    const int* __restrict__ deg_i, const int* __restrict__ bsums,
    int* __restrict__ off, int* __restrict__ cursor, int n)
{
    __shared__ int s[256];
    __shared__ int sbp;
    int b = blockIdx.x;
    int t = threadIdx.x;
    if (t < 64) {
        int v = (t < b) ? bsums[t] : 0;      // b <= 48 < 64
        #pragma unroll
        for (int m = 1; m < 64; m <<= 1) v += __shfl_xor(v, m, 64);
        if (t == 0) sbp = v;
    }
    int base = b * SCAN_TILE;
    int v4[4];
    int sum = 0;
    #pragma unroll
    for (int j = 0; j < 4; ++j) {
        int i = base + t * 4 + j;
        v4[j] = (i < n) ? deg_i[i] : 0;
        sum += v4[j];
    }
    s[t] = sum;
    __syncthreads();
    for (int o = 1; o < 256; o <<= 1) {
        int tmp = (t >= o) ? s[t - o] : 0;
        __syncthreads();
        s[t] += tmp;
        __syncthreads();
    }
    int run = s[t] - sum + sbp;
    #pragma unroll
    for (int j = 0; j < 4; ++j) {
        int i = base + t * 4 + j;
        if (i < n) { off[i] = run; cursor[i] = run; }
        run += v4[j];
    }
    if (b == N_SCAN_BLK - 1 && t == 255) off[n] = sbp + s[255];
}

// ---------------------------------------------------------------------------
// Stage 3: XCD-range-partitioned scatter via atomic cursor (round-7 proven).
// cursor/adj lines for a range are written by one XCD only.
// ---------------------------------------------------------------------------
__global__ __launch_bounds__(256) void scatter_kernel(
    const int* __restrict__ src, const int* __restrict__ dst,
    int* __restrict__ cursor, int* __restrict__ adj, int n_edges)
{
    int g = blockIdx.x & 7;
    int lo = g * RANGE_SZ;
    for (int e = (blockIdx.x >> 3) * 256 + threadIdx.x; e < n_edges; e += 65536) {
        int d = dst[e];
        if ((unsigned)(d - lo) < (unsigned)RANGE_SZ) {
            int p = atomicAdd(&cursor[d], 1);
            adj[p] = src[e];
        }
    }
}

// ---------------------------------------------------------------------------
// Gather-mean on bf16 x: agg[node] = mean of neighbors' xh rows (128B each).
// One wave per node, TWO edges per load instr: lanes 0-31 = even edge,
// lanes 32-63 = odd edge; lane's u32 = feature pair (2*(lane&31), +1).
// Fold halves with one shfl_xor(32). Source = 6.4MB, ~L2-resident.
// ---------------------------------------------------------------------------
__global__ __launch_bounds__(256) void gather_mean_kernel(
    const unsigned* __restrict__ xh,
    const int* __restrict__ adj,
    const int* __restrict__ off,
    unsigned* __restrict__ agg)
{
    int t = threadIdx.x;
    int wave = t >> 6, lane = t & 63;
    int node = blockIdx.x * 4 + wave;     // 12500 blocks * 4 = 50000 exact
    int o = off[node];
    int d = off[node + 1] - o;
    int half = lane >> 5;
    int col = lane & 31;
    float sx = 0.f, sy = 0.f;

    for (int j0 = 0; j0 < d; j0 += 64) {
        int c = d - j0; if (c > 64) c = 64;
        int nid = (lane < c) ? adj[o + j0 + lane] : 0;
        int j = 0;
        for (; j + 8 <= c; j += 8) {
            #pragma unroll
            for (int m = 0; m < 4; ++m) {
                int re = bl_i(nid, j + 2 * m);
                int ro = bl_i(nid, j + 2 * m + 1);
                int row = half ? ro : re;
                unsigned u = xh[(size_t)row * 32 + col];
                sx += uf(u << 16); sy += uf(u & 0xFFFF0000u);
            }
        }
        for (; j < c; j += 2) {
            int re = bl_i(nid, j);
            int ro = (j + 1 < c) ? bl_i(nid, j + 1) : re;
            int row = half ? ro : re;
            unsigned u = xh[(size_t)row * 32 + col];
            if (half && j + 1 >= c) u = 0u;
            sx += uf(u << 16); sy += uf(u & 0xFFFF0000u);
        }
    }
    sx += __shfl_xor(sx, 32, 64);
    sy += __shfl_xor(sy, 32, 64);
    if (half == 0) {
        float inv = 1.0f / fmaxf((float)d, 1.0f);
        agg[(size_t)node * 32 + col] = pk_bf16(sx * inv, sy * inv);
    }
}

// ---------------------------------------------------------------------------
// MFMA GEMM: emb = [x | agg] @ [[Ws],[Wn]] + b  (M=50000, K=128, N=128).
// W packed bf16-K-pairs in LDS ([64][129] u32, padded vs bank aliasing).
// One 16-row tile per wave; 782 blocks x 4 waves.
// ---------------------------------------------------------------------------
__global__ __launch_bounds__(256) void gemm_kernel(
    const unsigned* __restrict__ xh,
    const unsigned* __restrict__ agg,
    const float* __restrict__ Wn,
    const float* __restrict__ Ws,
    const float* __restrict__ bias,
    float* __restrict__ emb_out)
{
    __shared__ unsigned sWk[64 * 129];   // sWk[kk][n] = pack(Wf[2kk][n], Wf[2kk+1][n])
    __shared__ float sb[128];
    int t = threadIdx.x;
    for (int e = t; e < 64 * 128; e += 256) {
        int kk = e >> 7, n = e & 127;
        float w0, w1;
        if (kk < 32) { w0 = Ws[(2 * kk) * 128 + n];      w1 = Ws[(2 * kk + 1) * 128 + n]; }
        else         { w0 = Wn[(2 * kk - 64) * 128 + n]; w1 = Wn[(2 * kk - 63) * 128 + n]; }
        sWk[kk * 129 + n] = pk_bf16(w0, w1);
    }
    if (t < 128) sb[t] = bias[t];
    __syncthreads();

    int wave = t >> 6, lane = t & 63;
    int lr = lane & 15, lg = lane >> 4;
    int tile = blockIdx.x * 4 + wave;
    if (tile >= N_TILES) return;

    // A frags: row = tile*16 + lr; s=0,1 from xh (k 0..63), s=2,3 from agg
    const uint4* xr = (const uint4*)(xh + ((size_t)tile * 16 + lr) * 32);
    const uint4* ar = (const uint4*)(agg + ((size_t)tile * 16 + lr) * 32);
    U8 A[4];
    A[0].q = xr[lg];
    A[1].q = xr[4 + lg];
    A[2].q = ar[lg];
    A[3].q = ar[4 + lg];

    #pragma unroll
    for (int c = 0; c < 8; ++c) {
        float bv = sb[c * 16 + lr];
        f32x4 acc = {bv, bv, bv, bv};
        #pragma unroll
        for (int s = 0; s < 4; ++s) {
            U8 B;
            #pragma unroll
            for (int jj = 0; jj < 4; ++jj)
                B.u[jj] = sWk[(16 * s + 4 * lg + jj) * 129 + c * 16 + lr];
            acc = __builtin_amdgcn_mfma_f32_16x16x32_bf16(A[s].s, B.s, acc, 0, 0, 0);
        }
        #pragma unroll
        for (int r = 0; r < 4; ++r)
            emb_out[((size_t)tile * 16 + lg * 4 + r) * 128 + c * 16 + lr] = acc[r];
    }
}

// ---------------------------------------------------------------------------
// Fused segment mean-pool of relu(emb) + MLP head + log_softmax.
// ---------------------------------------------------------------------------
__global__ __launch_bounds__(256) void poolhead_kernel(
    const float* __restrict__ emb, const int* __restrict__ start,
    const float* __restrict__ W1, const float* __restrict__ b1,
    const float* __restrict__ W2, const float* __restrict__ b2,
    float* __restrict__ logits_out)
{
    int g = blockIdx.x;
    int t = threadIdx.x;
    __shared__ float sp[HID_C];
    __shared__ float shid[MLP_HID_C];
    __shared__ float sl[N_CLS_C];
    __shared__ float4 red[256];

    int s0 = start[g], e0 = start[g + 1];
    int q = t & 31, r0 = t >> 5;
    const float4* e4 = (const float4*)emb;
    float4 acc = make_float4(0.f, 0.f, 0.f, 0.f);
    for (int r = s0 + r0; r < e0; r += 8) {
        float4 v = e4[(size_t)r * 32 + q];
        acc.x += fmaxf(v.x, 0.f); acc.y += fmaxf(v.y, 0.f);
        acc.z += fmaxf(v.z, 0.f); acc.w += fmaxf(v.w, 0.f);
    }
    red[t] = acc;
    __syncthreads();
    if (t < 32) {
        float4 a = red[t];
        #pragma unroll
        for (int r = 1; r < 8; ++r) {
            float4 b = red[t + 32 * r];
            a.x += b.x; a.y += b.y; a.z += b.z; a.w += b.w;
        }
        float inv = 1.0f / fmaxf((float)(e0 - s0), 1.0f);
        ((float4*)sp)[t] = make_float4(a.x * inv, a.y * inv, a.z * inv, a.w * inv);
    }
    __syncthreads();

    if (t < MLP_HID_C) {
        float a = b1[t];
        #pragma unroll 8
        for (int k = 0; k < HID_C; ++k) a += sp[k] * W1[k * MLP_HID_C + t];
        shid[t] = fmaxf(a, 0.0f);
    }
    __syncthreads();

    if (t < N_CLS_C) {
        float a = b2[t];
        #pragma unroll
        for (int k = 0; k < MLP_HID_C; ++k) a += shid[k] * W2[k * N_CLS_C + t];
        sl[t] = a;
    }
    __syncthreads();

    if (t < N_CLS_C) {
        float m = sl[0];
        #pragma unroll
        for (int i = 1; i < N_CLS_C; ++i) m = fmaxf(m, sl[i]);
        float sum = 0.0f;
        #pragma unroll
        for (int i = 0; i < N_CLS_C; ++i) sum += expf(sl[i] - m);
        logits_out[(size_t)g * N_CLS_C + t] = sl[t] - m - logf(sum);
    }
}

extern "C" void kernel_launch(void* const* d_in, const int* in_sizes, int n_in,
                              void* d_out, int out_size, void* d_ws, size_t ws_size,
                              hipStream_t stream) {
    const float* x      = (const float*)d_in[0];
    const int*   ei     = (const int*)d_in[1];
    const int*   batch  = (const int*)d_in[2];
    const float* Wn     = (const float*)d_in[3];
    const float* Ws     = (const float*)d_in[4];
    const float* bias   = (const float*)d_in[5];
    const float* W1     = (const float*)d_in[6];
    const float* b1     = (const float*)d_in[7];
    const float* W2     = (const float*)d_in[8];
    const float* b2     = (const float*)d_in[9];

    float* out = (float*)d_out;
    int n_edges = in_sizes[1] / 2;
    const int* src = ei;
    const int* dst = ei + n_edges;

    // ws (ints): deg_i[N] | off[N+1] | cursor[N] | bsums[64] | start[G+1] |
    //            pad[2] | xh[N*32] | adj[E] | agg[N*32]
    int* deg_i   = (int*)d_ws;
    int* off     = deg_i + N_NODES_C;
    int* cursor  = off + (N_NODES_C + 1);
    int* bsums   = cursor + N_NODES_C;
    int* start   = bsums + 64;
    unsigned* xh = (unsigned*)(start + (N_GRAPHS_C + 1) + 2);   // 16B-aligned
    int* adj     = (int*)(xh + (size_t)N_NODES_C * 32);
    unsigned* agg = (unsigned*)(adj + n_edges);

    hipMemsetAsync(deg_i, 0, (size_t)N_NODES_C * sizeof(int), stream);

    hist_kernel<<<2048, 256, 0, stream>>>(dst, batch, x, deg_i, xh, start, n_edges);
    scan1_kernel<<<N_SCAN_BLK, 256, 0, stream>>>(deg_i, bsums, N_NODES_C);
    scan3_kernel<<<N_SCAN_BLK, 256, 0, stream>>>(deg_i, bsums, off, cursor, N_NODES_C);
    scatter_kernel<<<2048, 256, 0, stream>>>(src, dst, cursor, adj, n_edges);

    gather_mean_kernel<<<12500, 256, 0, stream>>>(xh, adj, off, agg);

    gemm_kernel<<<782, 256, 0, stream>>>(xh, agg, Wn, Ws, bias, out);

    poolhead_kernel<<<N_GRAPHS_C, 256, 0, stream>>>(out, start, W1, b1, W2, b2,
                                                    out + (size_t)N_NODES_C * HID_C);
}

// Round 10
// 120.037 us; speedup vs baseline: 1.1830x; 1.1830x over previous
//
#include <hip/hip_runtime.h>

#define N_NODES_C 50000
#define F_IN_C 64
#define HID_C 128
#define N_GRAPHS_C 500
#define N_CLS_C 10
#define MLP_HID_C 50
#define SCAN_TILE 1024
#define N_SCAN_BLK ((N_NODES_C + SCAN_TILE - 1) / SCAN_TILE)   // 49
#define N_TILES (N_NODES_C / 16)                               // 3125
#define N_RANGES 8
#define RANGE_SZ (N_NODES_C / N_RANGES)                        // 6250 (exact)
#define S_STRIPES 16

using short8 = __attribute__((ext_vector_type(8))) short;
using f32x4  = __attribute__((ext_vector_type(4))) float;

__device__ __forceinline__ int bl_i(int v, int l) {
    return __builtin_amdgcn_readlane(v, l);
}
__device__ __forceinline__ float uf(unsigned u) { return __uint_as_float(u); }

// round-to-nearest-even bf16 pack of two floats -> (lo=a, hi=b)
__device__ __forceinline__ unsigned pk_bf16(float a, float b) {
    unsigned ua = __float_as_uint(a), ub = __float_as_uint(b);
    ua += 0x7FFFu + ((ua >> 16) & 1u);
    ub += 0x7FFFu + ((ub >> 16) & 1u);
    return (ua >> 16) | (ub & 0xFFFF0000u);
}

union U8 { unsigned u[4]; uint4 q; short8 s; };

// ---------------------------------------------------------------------------
// Prep: bf16-compress x + graph bounds. Pure streaming, no atomics.
// ---------------------------------------------------------------------------
__global__ __launch_bounds__(256) void prep_kernel(
    const float* __restrict__ x,
    const int* __restrict__ batch,
    unsigned* __restrict__ xh,
    int* __restrict__ start)
{
    int tid = blockIdx.x * 256 + threadIdx.x;
    int stride = gridDim.x * 256;
    const float2* xf2 = (const float2*)x;
    int nx = N_NODES_C * (F_IN_C / 2);
    for (int i = tid; i < nx; i += stride) {
        float2 v = xf2[i];
        xh[i] = pk_bf16(v.x, v.y);
    }
    for (int i = tid; i < N_NODES_C; i += stride) {
        int b = batch[i];
        if (i == 0) { for (int g = 0; g <= b; ++g) start[g] = 0; }
        else { int p = batch[i - 1]; for (int g = p + 1; g <= b; ++g) start[g] = i; }
        if (i == N_NODES_C - 1) { for (int g = b + 1; g <= N_GRAPHS_C; ++g) start[g] = N_NODES_C; }
    }
}

// ---------------------------------------------------------------------------
// hist2d: block (s,r) = (blockIdx>>3, blockIdx&7) builds an LDS histogram of
// node-range r over edge-stripe s. No global atomics; h[s][*] written
// exclusively & coalesced.
// ---------------------------------------------------------------------------
__global__ __launch_bounds__(1024) void hist2d_kernel(
    const int* __restrict__ dst, int* __restrict__ h, int n_edges, int stripe)
{
    __shared__ int lh[RANGE_SZ];
    int s = blockIdx.x >> 3, r = blockIdx.x & 7;
    int lo = r * RANGE_SZ;
    int t = threadIdx.x;
    for (int i = t; i < RANGE_SZ; i += 1024) lh[i] = 0;
    __syncthreads();
    int e1 = min(n_edges, (s + 1) * stripe);
    for (int e = s * stripe + t; e < e1; e += 1024) {
        int d = dst[e] - lo;
        if ((unsigned)d < (unsigned)RANGE_SZ) atomicAdd(&lh[d], 1);
    }
    __syncthreads();
    for (int i = t; i < RANGE_SZ; i += 1024)
        h[s * N_NODES_C + lo + i] = lh[i];
}

// ---------------------------------------------------------------------------
// reduce: per node, exclusive prefix over stripe counts -> p[s][n]; total ->
// deg_i[n]. All coalesced; replaces the memset too.
// ---------------------------------------------------------------------------
__global__ __launch_bounds__(256) void reduce_kernel(
    const int* __restrict__ h, int* __restrict__ p, int* __restrict__ deg_i)
{
    int n = blockIdx.x * 256 + threadIdx.x;
    if (n >= N_NODES_C) return;
    int run = 0;
    #pragma unroll
    for (int s = 0; s < S_STRIPES; ++s) {
        int c = h[s * N_NODES_C + n];
        p[s * N_NODES_C + n] = run;
        run += c;
    }
    deg_i[n] = run;
}

// Stage 2a: per-1024-tile sums
__global__ __launch_bounds__(256) void scan1_kernel(
    const int* __restrict__ deg_i, int* __restrict__ bsums, int n)
{
    __shared__ int s[256];
    int base = blockIdx.x * SCAN_TILE;
    int t = threadIdx.x;
    int sum = 0;
    #pragma unroll
    for (int j = 0; j < 4; ++j) {
        int i = base + t * 4 + j;
        sum += (i < n) ? deg_i[i] : 0;
    }
    s[t] = sum;
    __syncthreads();
    for (int off = 128; off > 0; off >>= 1) {
        if (t < off) s[t] += s[t + off];
        __syncthreads();
    }
    if (t == 0) bsums[blockIdx.x] = s[0];
}

// Stage 2b: tile-prefix via wave-reduce of bsums + intra-tile exclusive scan
__global__ __launch_bounds__(256) void scan3_kernel(
    const int* __restrict__ deg_i, const int* __restrict__ bsums,
    int* __restrict__ off, int n)
{
    __shared__ int s[256];
    __shared__ int sbp;
    int b = blockIdx.x;
    int t = threadIdx.x;
    if (t < 64) {
        int v = (t < b) ? bsums[t] : 0;      // b <= 48 < 64
        #pragma unroll
        for (int m = 1; m < 64; m <<= 1) v += __shfl_xor(v, m, 64);
        if (t == 0) sbp = v;
    }
    int base = b * SCAN_TILE;
    int v4[4];
    int sum = 0;
    #pragma unroll
    for (int j = 0; j < 4; ++j) {
        int i = base + t * 4 + j;
        v4[j] = (i < n) ? deg_i[i] : 0;
        sum += v4[j];
    }
    s[t] = sum;
    __syncthreads();
    for (int o = 1; o < 256; o <<= 1) {
        int tmp = (t >= o) ? s[t - o] : 0;
        __syncthreads();
        s[t] += tmp;
        __syncthreads();
    }
    int run = s[t] - sum + sbp;
    #pragma unroll
    for (int j = 0; j < 4; ++j) {
        int i = base + t * 4 + j;
        if (i < n) off[i] = run;
        run += v4[j];
    }
    if (b == N_SCAN_BLK - 1 && t == 255) off[n] = sbp + s[255];
}

// ---------------------------------------------------------------------------
// scatter2d: block (s,r) places stripe-s edges of range r using LDS cursors
// seeded with off[d] + p[s][d]. Slots are globally unique by construction ->
// plain stores, zero global atomics. adj writes stay in the range's
// contiguous 400KB region.
// ---------------------------------------------------------------------------
__global__ __launch_bounds__(1024) void scatter2d_kernel(
    const int* __restrict__ src, const int* __restrict__ dst,
    const int* __restrict__ off, const int* __restrict__ p,
    int* __restrict__ adj, int n_edges, int stripe)
{
    __shared__ int lcur[RANGE_SZ];
    int s = blockIdx.x >> 3, r = blockIdx.x & 7;
    int lo = r * RANGE_SZ;
    int t = threadIdx.x;
    for (int i = t; i < RANGE_SZ; i += 1024)
        lcur[i] = off[lo + i] + p[s * N_NODES_C + lo + i];
    __syncthreads();
    int e1 = min(n_edges, (s + 1) * stripe);
    for (int e = s * stripe + t; e < e1; e += 1024) {
        int d = dst[e] - lo;
        if ((unsigned)d < (unsigned)RANGE_SZ) {
            int pos = atomicAdd(&lcur[d], 1);
            adj[pos] = src[e];
        }
    }
}

// ---------------------------------------------------------------------------
// Gather-mean on bf16 x: agg[node] = mean of neighbors' xh rows (128B each).
// One wave per node, TWO edges per load instr (lanes 0-31 / 32-63), fold via
// one shfl_xor(32). Source = 6.4MB, ~L2-resident.
// ---------------------------------------------------------------------------
__global__ __launch_bounds__(256) void gather_mean_kernel(
    const unsigned* __restrict__ xh,
    const int* __restrict__ adj,
    const int* __restrict__ off,
    unsigned* __restrict__ agg)
{
    int t = threadIdx.x;
    int wave = t >> 6, lane = t & 63;
    int node = blockIdx.x * 4 + wave;     // 12500 blocks * 4 = 50000 exact
    int o = off[node];
    int d = off[node + 1] - o;
    int half = lane >> 5;
    int col = lane & 31;
    float sx = 0.f, sy = 0.f;

    for (int j0 = 0; j0 < d; j0 += 64) {
        int c = d - j0; if (c > 64) c = 64;
        int nid = (lane < c) ? adj[o + j0 + lane] : 0;
        int j = 0;
        for (; j + 8 <= c; j += 8) {
            #pragma unroll
            for (int m = 0; m < 4; ++m) {
                int re = bl_i(nid, j + 2 * m);
                int ro = bl_i(nid, j + 2 * m + 1);
                int row = half ? ro : re;
                unsigned u = xh[(size_t)row * 32 + col];
                sx += uf(u << 16); sy += uf(u & 0xFFFF0000u);
            }
        }
        for (; j < c; j += 2) {
            int re = bl_i(nid, j);
            int ro = (j + 1 < c) ? bl_i(nid, j + 1) : re;
            int row = half ? ro : re;
            unsigned u = xh[(size_t)row * 32 + col];
            if (half && j + 1 >= c) u = 0u;
            sx += uf(u << 16); sy += uf(u & 0xFFFF0000u);
        }
    }
    sx += __shfl_xor(sx, 32, 64);
    sy += __shfl_xor(sy, 32, 64);
    if (half == 0) {
        float inv = 1.0f / fmaxf((float)d, 1.0f);
        agg[(size_t)node * 32 + col] = pk_bf16(sx * inv, sy * inv);
    }
}

// ---------------------------------------------------------------------------
// MFMA GEMM: emb = [x | agg] @ [[Ws],[Wn]] + b  (M=50000, K=128, N=128).
// W packed bf16-K-pairs in LDS ([64][129] u32, padded vs bank aliasing).
// ---------------------------------------------------------------------------
__global__ __launch_bounds__(256) void gemm_kernel(
    const unsigned* __restrict__ xh,
    const unsigned* __restrict__ agg,
    const float* __restrict__ Wn,
    const float* __restrict__ Ws,
    const float* __restrict__ bias,
    float* __restrict__ emb_out)
{
    __shared__ unsigned sWk[64 * 129];   // sWk[kk][n] = pack(Wf[2kk][n], Wf[2kk+1][n])
    __shared__ float sb[128];
    int t = threadIdx.x;
    for (int e = t; e < 64 * 128; e += 256) {
        int kk = e >> 7, n = e & 127;
        float w0, w1;
        if (kk < 32) { w0 = Ws[(2 * kk) * 128 + n];      w1 = Ws[(2 * kk + 1) * 128 + n]; }
        else         { w0 = Wn[(2 * kk - 64) * 128 + n]; w1 = Wn[(2 * kk - 63) * 128 + n]; }
        sWk[kk * 129 + n] = pk_bf16(w0, w1);
    }
    if (t < 128) sb[t] = bias[t];
    __syncthreads();

    int wave = t >> 6, lane = t & 63;
    int lr = lane & 15, lg = lane >> 4;
    int tile = blockIdx.x * 4 + wave;
    if (tile >= N_TILES) return;

    const uint4* xr = (const uint4*)(xh + ((size_t)tile * 16 + lr) * 32);
    const uint4* ar = (const uint4*)(agg + ((size_t)tile * 16 + lr) * 32);
    U8 A[4];
    A[0].q = xr[lg];
    A[1].q = xr[4 + lg];
    A[2].q = ar[lg];
    A[3].q = ar[4 + lg];

    #pragma unroll
    for (int c = 0; c < 8; ++c) {
        float bv = sb[c * 16 + lr];
        f32x4 acc = {bv, bv, bv, bv};
        #pragma unroll
        for (int s = 0; s < 4; ++s) {
            U8 B;
            #pragma unroll
            for (int jj = 0; jj < 4; ++jj)
                B.u[jj] = sWk[(16 * s + 4 * lg + jj) * 129 + c * 16 + lr];
            acc = __builtin_amdgcn_mfma_f32_16x16x32_bf16(A[s].s, B.s, acc, 0, 0, 0);
        }
        #pragma unroll
        for (int r = 0; r < 4; ++r)
            emb_out[((size_t)tile * 16 + lg * 4 + r) * 128 + c * 16 + lr] = acc[r];
    }
}

// ---------------------------------------------------------------------------
// Fused segment mean-pool of relu(emb) + MLP head + log_softmax.
// ---------------------------------------------------------------------------
__global__ __launch_bounds__(256) void poolhead_kernel(
    const float* __restrict__ emb, const int* __restrict__ start,
    const float* __restrict__ W1, const float* __restrict__ b1,
    const float* __restrict__ W2, const float* __restrict__ b2,
    float* __restrict__ logits_out)
{
    int g = blockIdx.x;
    int t = threadIdx.x;
    __shared__ float sp[HID_C];
    __shared__ float shid[MLP_HID_C];
    __shared__ float sl[N_CLS_C];
    __shared__ float4 red[256];

    int s0 = start[g], e0 = start[g + 1];
    int q = t & 31, r0 = t >> 5;
    const float4* e4 = (const float4*)emb;
    float4 acc = make_float4(0.f, 0.f, 0.f, 0.f);
    for (int r = s0 + r0; r < e0; r += 8) {
        float4 v = e4[(size_t)r * 32 + q];
        acc.x += fmaxf(v.x, 0.f); acc.y += fmaxf(v.y, 0.f);
        acc.z += fmaxf(v.z, 0.f); acc.w += fmaxf(v.w, 0.f);
    }
    red[t] = acc;
    __syncthreads();
    if (t < 32) {
        float4 a = red[t];
        #pragma unroll
        for (int r = 1; r < 8; ++r) {
            float4 b = red[t + 32 * r];
            a.x += b.x; a.y += b.y; a.z += b.z; a.w += b.w;
        }
        float inv = 1.0f / fmaxf((float)(e0 - s0), 1.0f);
        ((float4*)sp)[t] = make_float4(a.x * inv, a.y * inv, a.z * inv, a.w * inv);
    }
    __syncthreads();

    if (t < MLP_HID_C) {
        float a = b1[t];
        #pragma unroll 8
        for (int k = 0; k < HID_C; ++k) a += sp[k] * W1[k * MLP_HID_C + t];
        shid[t] = fmaxf(a, 0.0f);
    }
    __syncthreads();

    if (t < N_CLS_C) {
        float a = b2[t];
        #pragma unroll
        for (int k = 0; k < MLP_HID_C; ++k) a += shid[k] * W2[k * N_CLS_C + t];
        sl[t] = a;
    }
    __syncthreads();

    if (t < N_CLS_C) {
        float m = sl[0];
        #pragma unroll
        for (int i = 1; i < N_CLS_C; ++i) m = fmaxf(m, sl[i]);
        float sum = 0.0f;
        #pragma unroll
        for (int i = 0; i < N_CLS_C; ++i) sum += expf(sl[i] - m);
        logits_out[(size_t)g * N_CLS_C + t] = sl[t] - m - logf(sum);
    }
}

extern "C" void kernel_launch(void* const* d_in, const int* in_sizes, int n_in,
                              void* d_out, int out_size, void* d_ws, size_t ws_size,
                              hipStream_t stream) {
    const float* x      = (const float*)d_in[0];
    const int*   ei     = (const int*)d_in[1];
    const int*   batch  = (const int*)d_in[2];
    const float* Wn     = (const float*)d_in[3];
    const float* Ws     = (const float*)d_in[4];
    const float* bias   = (const float*)d_in[5];
    const float* W1     = (const float*)d_in[6];
    const float* b1     = (const float*)d_in[7];
    const float* W2     = (const float*)d_in[8];
    const float* b2     = (const float*)d_in[9];

    float* out = (float*)d_out;
    int n_edges = in_sizes[1] / 2;
    const int* src = ei;
    const int* dst = ei + n_edges;
    int stripe = (n_edges + S_STRIPES - 1) / S_STRIPES;

    // ws (ints): deg_i[N] | off[N+1] | bsums[64] | start[G+1] | pad[2] |
    //            xh[N*32] | adj[E(pad4)] | agg[N*32]
    // h,p (S*N each = 1.6M ints total) alias agg (dead before gather writes).
    int* deg_i   = (int*)d_ws;
    int* off     = deg_i + N_NODES_C;
    int* bsums   = off + (N_NODES_C + 1);
    int* start   = bsums + 64;
    unsigned* xh = (unsigned*)(start + (N_GRAPHS_C + 1) + 2);   // 16B-aligned
    int* adj     = (int*)(xh + (size_t)N_NODES_C * 32);
    unsigned* agg = (unsigned*)(adj + ((n_edges + 3) & ~3));
    int* h       = (int*)agg;
    int* p       = h + (size_t)S_STRIPES * N_NODES_C;

    prep_kernel<<<1024, 256, 0, stream>>>(x, batch, xh, start);
    hist2d_kernel<<<S_STRIPES * N_RANGES, 1024, 0, stream>>>(dst, h, n_edges, stripe);
    reduce_kernel<<<(N_NODES_C + 255) / 256, 256, 0, stream>>>(h, p, deg_i);
    scan1_kernel<<<N_SCAN_BLK, 256, 0, stream>>>(deg_i, bsums, N_NODES_C);
    scan3_kernel<<<N_SCAN_BLK, 256, 0, stream>>>(deg_i, bsums, off, N_NODES_C);
    scatter2d_kernel<<<S_STRIPES * N_RANGES, 1024, 0, stream>>>(src, dst, off, p,
                                                                adj, n_edges, stripe);

    gather_mean_kernel<<<12500, 256, 0, stream>>>(xh, adj, off, agg);

    gemm_kernel<<<782, 256, 0, stream>>>(xh, agg, Wn, Ws, bias, out);

    poolhead_kernel<<<N_GRAPHS_C, 256, 0, stream>>>(out, start, W1, b1, W2, b2,
                                                    out + (size_t)N_NODES_C * HID_C);
}

// Round 11
// 94.158 us; speedup vs baseline: 1.5081x; 1.2748x over previous
//
#include <hip/hip_runtime.h>

#define N_NODES_C 50000
#define F_IN_C 64
#define HID_C 128
#define N_GRAPHS_C 500
#define N_CLS_C 10
#define MLP_HID_C 50
#define SCAN_TILE 1024
#define N_SCAN_BLK ((N_NODES_C + SCAN_TILE - 1) / SCAN_TILE)   // 49
#define N_TILES (N_NODES_C / 16)                               // 3125
#define N_RANGES 8
#define RANGE_SZ (N_NODES_C / N_RANGES)                        // 6250 (exact)
#define S_STRIPES 64

using short8 = __attribute__((ext_vector_type(8))) short;
using f32x4  = __attribute__((ext_vector_type(4))) float;

__device__ __forceinline__ int bl_i(int v, int l) {
    return __builtin_amdgcn_readlane(v, l);
}
__device__ __forceinline__ float uf(unsigned u) { return __uint_as_float(u); }

// round-to-nearest-even bf16 pack of two floats -> (lo=a, hi=b)
__device__ __forceinline__ unsigned pk_bf16(float a, float b) {
    unsigned ua = __float_as_uint(a), ub = __float_as_uint(b);
    ua += 0x7FFFu + ((ua >> 16) & 1u);
    ub += 0x7FFFu + ((ub >> 16) & 1u);
    return (ua >> 16) | (ub & 0xFFFF0000u);
}

union U8 { unsigned u[4]; uint4 q; short8 s; };

// ---------------------------------------------------------------------------
// Prep: bf16-compress x + graph bounds. Pure streaming, no atomics.
// ---------------------------------------------------------------------------
__global__ __launch_bounds__(256) void prep_kernel(
    const float* __restrict__ x,
    const int* __restrict__ batch,
    unsigned* __restrict__ xh,
    int* __restrict__ start)
{
    int tid = blockIdx.x * 256 + threadIdx.x;
    int stride = gridDim.x * 256;
    const float2* xf2 = (const float2*)x;
    int nx = N_NODES_C * (F_IN_C / 2);
    for (int i = tid; i < nx; i += stride) {
        float2 v = xf2[i];
        xh[i] = pk_bf16(v.x, v.y);
    }
    for (int i = tid; i < N_NODES_C; i += stride) {
        int b = batch[i];
        if (i == 0) { for (int g = 0; g <= b; ++g) start[g] = 0; }
        else { int p = batch[i - 1]; for (int g = p + 1; g <= b; ++g) start[g] = i; }
        if (i == N_NODES_C - 1) { for (int g = b + 1; g <= N_GRAPHS_C; ++g) start[g] = N_NODES_C; }
    }
}

// ---------------------------------------------------------------------------
// hist2d: block (s,r) = (blockIdx>>3, blockIdx&7) builds an LDS histogram of
// node-range r over edge-stripe s. No global atomics. Grid 512 = 2 blocks/CU.
// ---------------------------------------------------------------------------
__global__ __launch_bounds__(1024) void hist2d_kernel(
    const int* __restrict__ dst, int* __restrict__ h, int n_edges, int stripe)
{
    __shared__ int lh[RANGE_SZ];
    int s = blockIdx.x >> 3, r = blockIdx.x & 7;
    int lo = r * RANGE_SZ;
    int t = threadIdx.x;
    for (int i = t; i < RANGE_SZ; i += 1024) lh[i] = 0;
    __syncthreads();
    int e1 = min(n_edges, (s + 1) * stripe);
    for (int e = s * stripe + t; e < e1; e += 1024) {
        int d = dst[e] - lo;
        if ((unsigned)d < (unsigned)RANGE_SZ) atomicAdd(&lh[d], 1);
    }
    __syncthreads();
    for (int i = t; i < RANGE_SZ; i += 1024)
        h[(size_t)s * N_NODES_C + lo + i] = lh[i];
}

// ---------------------------------------------------------------------------
// reduce: per node, exclusive prefix over stripe counts -> p[s][n]; total ->
// deg_i[n]. All coalesced; replaces the memset too.
// ---------------------------------------------------------------------------
__global__ __launch_bounds__(256) void reduce_kernel(
    const int* __restrict__ h, int* __restrict__ p, int* __restrict__ deg_i)
{
    int n = blockIdx.x * 256 + threadIdx.x;
    if (n >= N_NODES_C) return;
    int run = 0;
    #pragma unroll 8
    for (int s = 0; s < S_STRIPES; ++s) {
        int c = h[(size_t)s * N_NODES_C + n];
        p[(size_t)s * N_NODES_C + n] = run;
        run += c;
    }
    deg_i[n] = run;
}

// Stage 2a: per-1024-tile sums
__global__ __launch_bounds__(256) void scan1_kernel(
    const int* __restrict__ deg_i, int* __restrict__ bsums, int n)
{
    __shared__ int s[256];
    int base = blockIdx.x * SCAN_TILE;
    int t = threadIdx.x;
    int sum = 0;
    #pragma unroll
    for (int j = 0; j < 4; ++j) {
        int i = base + t * 4 + j;
        sum += (i < n) ? deg_i[i] : 0;
    }
    s[t] = sum;
    __syncthreads();
    for (int off = 128; off > 0; off >>= 1) {
        if (t < off) s[t] += s[t + off];
        __syncthreads();
    }
    if (t == 0) bsums[blockIdx.x] = s[0];
}

// Stage 2b: tile-prefix via wave-reduce of bsums + intra-tile exclusive scan
__global__ __launch_bounds__(256) void scan3_kernel(
    const int* __restrict__ deg_i, const int* __restrict__ bsums,
    int* __restrict__ off, int n)
{
    __shared__ int s[256];
    __shared__ int sbp;
    int b = blockIdx.x;
    int t = threadIdx.x;
    if (t < 64) {
        int v = (t < b) ? bsums[t] : 0;      // b <= 48 < 64
        #pragma unroll
        for (int m = 1; m < 64; m <<= 1) v += __shfl_xor(v, m, 64);
        if (t == 0) sbp = v;
    }
    int base = b * SCAN_TILE;
    int v4[4];
    int sum = 0;
    #pragma unroll
    for (int j = 0; j < 4; ++j) {
        int i = base + t * 4 + j;
        v4[j] = (i < n) ? deg_i[i] : 0;
        sum += v4[j];
    }
    s[t] = sum;
    __syncthreads();
    for (int o = 1; o < 256; o <<= 1) {
        int tmp = (t >= o) ? s[t - o] : 0;
        __syncthreads();
        s[t] += tmp;
        __syncthreads();
    }
    int run = s[t] - sum + sbp;
    #pragma unroll
    for (int j = 0; j < 4; ++j) {
        int i = base + t * 4 + j;
        if (i < n) off[i] = run;
        run += v4[j];
    }
    if (b == N_SCAN_BLK - 1 && t == 255) off[n] = sbp + s[255];
}

// ---------------------------------------------------------------------------
// scatter2d: block (s,r) places stripe-s edges of range r using LDS cursors
// seeded with off[d] + p[s][d]. Globally unique slots -> plain stores, zero
// global atomics. Grid 512 = 2 blocks/CU.
// ---------------------------------------------------------------------------
__global__ __launch_bounds__(1024) void scatter2d_kernel(
    const int* __restrict__ src, const int* __restrict__ dst,
    const int* __restrict__ off, const int* __restrict__ p,
    int* __restrict__ adj, int n_edges, int stripe)
{
    __shared__ int lcur[RANGE_SZ];
    int s = blockIdx.x >> 3, r = blockIdx.x & 7;
    int lo = r * RANGE_SZ;
    int t = threadIdx.x;
    for (int i = t; i < RANGE_SZ; i += 1024)
        lcur[i] = off[lo + i] + p[(size_t)s * N_NODES_C + lo + i];
    __syncthreads();
    int e1 = min(n_edges, (s + 1) * stripe);
    for (int e = s * stripe + t; e < e1; e += 1024) {
        int d = dst[e] - lo;
        if ((unsigned)d < (unsigned)RANGE_SZ) {
            int pos = atomicAdd(&lcur[d], 1);
            adj[pos] = src[e];
        }
    }
}

// ---------------------------------------------------------------------------
// Gather-mean on bf16 x: agg[node] = mean of neighbors' xh rows (128B each).
// One wave per node, TWO edges per load instr (lanes 0-31 / 32-63), fold via
// one shfl_xor(32). Source = 6.4MB, ~L2-resident.
// ---------------------------------------------------------------------------
__global__ __launch_bounds__(256) void gather_mean_kernel(
    const unsigned* __restrict__ xh,
    const int* __restrict__ adj,
    const int* __restrict__ off,
    unsigned* __restrict__ agg)
{
    int t = threadIdx.x;
    int wave = t >> 6, lane = t & 63;
    int node = blockIdx.x * 4 + wave;     // 12500 blocks * 4 = 50000 exact
    int o = off[node];
    int d = off[node + 1] - o;
    int half = lane >> 5;
    int col = lane & 31;
    float sx = 0.f, sy = 0.f;

    for (int j0 = 0; j0 < d; j0 += 64) {
        int c = d - j0; if (c > 64) c = 64;
        int nid = (lane < c) ? adj[o + j0 + lane] : 0;
        int j = 0;
        for (; j + 8 <= c; j += 8) {
            #pragma unroll
            for (int m = 0; m < 4; ++m) {
                int re = bl_i(nid, j + 2 * m);
                int ro = bl_i(nid, j + 2 * m + 1);
                int row = half ? ro : re;
                unsigned u = xh[(size_t)row * 32 + col];
                sx += uf(u << 16); sy += uf(u & 0xFFFF0000u);
            }
        }
        for (; j < c; j += 2) {
            int re = bl_i(nid, j);
            int ro = (j + 1 < c) ? bl_i(nid, j + 1) : re;
            int row = half ? ro : re;
            unsigned u = xh[(size_t)row * 32 + col];
            if (half && j + 1 >= c) u = 0u;
            sx += uf(u << 16); sy += uf(u & 0xFFFF0000u);
        }
    }
    sx += __shfl_xor(sx, 32, 64);
    sy += __shfl_xor(sy, 32, 64);
    if (half == 0) {
        float inv = 1.0f / fmaxf((float)d, 1.0f);
        agg[(size_t)node * 32 + col] = pk_bf16(sx * inv, sy * inv);
    }
}

// ---------------------------------------------------------------------------
// MFMA GEMM: emb = [x | agg] @ [[Ws],[Wn]] + b  (M=50000, K=128, N=128).
// W packed bf16-K-pairs in LDS ([64][129] u32, padded vs bank aliasing).
// ---------------------------------------------------------------------------
__global__ __launch_bounds__(256) void gemm_kernel(
    const unsigned* __restrict__ xh,
    const unsigned* __restrict__ agg,
    const float* __restrict__ Wn,
    const float* __restrict__ Ws,
    const float* __restrict__ bias,
    float* __restrict__ emb_out)
{
    __shared__ unsigned sWk[64 * 129];   // sWk[kk][n] = pack(Wf[2kk][n], Wf[2kk+1][n])
    __shared__ float sb[128];
    int t = threadIdx.x;
    for (int e = t; e < 64 * 128; e += 256) {
        int kk = e >> 7, n = e & 127;
        float w0, w1;
        if (kk < 32) { w0 = Ws[(2 * kk) * 128 + n];      w1 = Ws[(2 * kk + 1) * 128 + n]; }
        else         { w0 = Wn[(2 * kk - 64) * 128 + n]; w1 = Wn[(2 * kk - 63) * 128 + n]; }
        sWk[kk * 129 + n] = pk_bf16(w0, w1);
    }
    if (t < 128) sb[t] = bias[t];
    __syncthreads();

    int wave = t >> 6, lane = t & 63;
    int lr = lane & 15, lg = lane >> 4;
    int tile = blockIdx.x * 4 + wave;
    if (tile >= N_TILES) return;

    const uint4* xr = (const uint4*)(xh + ((size_t)tile * 16 + lr) * 32);
    const uint4* ar = (const uint4*)(agg + ((size_t)tile * 16 + lr) * 32);
    U8 A[4];
    A[0].q = xr[lg];
    A[1].q = xr[4 + lg];
    A[2].q = ar[lg];
    A[3].q = ar[4 + lg];

    #pragma unroll
    for (int c = 0; c < 8; ++c) {
        float bv = sb[c * 16 + lr];
        f32x4 acc = {bv, bv, bv, bv};
        #pragma unroll
        for (int s = 0; s < 4; ++s) {
            U8 B;
            #pragma unroll
            for (int jj = 0; jj < 4; ++jj)
                B.u[jj] = sWk[(16 * s + 4 * lg + jj) * 129 + c * 16 + lr];
            acc = __builtin_amdgcn_mfma_f32_16x16x32_bf16(A[s].s, B.s, acc, 0, 0, 0);
        }
        #pragma unroll
        for (int r = 0; r < 4; ++r)
            emb_out[((size_t)tile * 16 + lg * 4 + r) * 128 + c * 16 + lr] = acc[r];
    }
}

// ---------------------------------------------------------------------------
// Fused segment mean-pool of relu(emb) + MLP head + log_softmax.
// ---------------------------------------------------------------------------
__global__ __launch_bounds__(256) void poolhead_kernel(
    const float* __restrict__ emb, const int* __restrict__ start,
    const float* __restrict__ W1, const float* __restrict__ b1,
    const float* __restrict__ W2, const float* __restrict__ b2,
    float* __restrict__ logits_out)
{
    int g = blockIdx.x;
    int t = threadIdx.x;
    __shared__ float sp[HID_C];
    __shared__ float shid[MLP_HID_C];
    __shared__ float sl[N_CLS_C];
    __shared__ float4 red[256];

    int s0 = start[g], e0 = start[g + 1];
    int q = t & 31, r0 = t >> 5;
    const float4* e4 = (const float4*)emb;
    float4 acc = make_float4(0.f, 0.f, 0.f, 0.f);
    for (int r = s0 + r0; r < e0; r += 8) {
        float4 v = e4[(size_t)r * 32 + q];
        acc.x += fmaxf(v.x, 0.f); acc.y += fmaxf(v.y, 0.f);
        acc.z += fmaxf(v.z, 0.f); acc.w += fmaxf(v.w, 0.f);
    }
    red[t] = acc;
    __syncthreads();
    if (t < 32) {
        float4 a = red[t];
        #pragma unroll
        for (int r = 1; r < 8; ++r) {
            float4 b = red[t + 32 * r];
            a.x += b.x; a.y += b.y; a.z += b.z; a.w += b.w;
        }
        float inv = 1.0f / fmaxf((float)(e0 - s0), 1.0f);
        ((float4*)sp)[t] = make_float4(a.x * inv, a.y * inv, a.z * inv, a.w * inv);
    }
    __syncthreads();

    if (t < MLP_HID_C) {
        float a = b1[t];
        #pragma unroll 8
        for (int k = 0; k < HID_C; ++k) a += sp[k] * W1[k * MLP_HID_C + t];
        shid[t] = fmaxf(a, 0.0f);
    }
    __syncthreads();

    if (t < N_CLS_C) {
        float a = b2[t];
        #pragma unroll
        for (int k = 0; k < MLP_HID_C; ++k) a += shid[k] * W2[k * N_CLS_C + t];
        sl[t] = a;
    }
    __syncthreads();

    if (t < N_CLS_C) {
        float m = sl[0];
        #pragma unroll
        for (int i = 1; i < N_CLS_C; ++i) m = fmaxf(m, sl[i]);
        float sum = 0.0f;
        #pragma unroll
        for (int i = 0; i < N_CLS_C; ++i) sum += expf(sl[i] - m);
        logits_out[(size_t)g * N_CLS_C + t] = sl[t] - m - logf(sum);
    }
}

extern "C" void kernel_launch(void* const* d_in, const int* in_sizes, int n_in,
                              void* d_out, int out_size, void* d_ws, size_t ws_size,
                              hipStream_t stream) {
    const float* x      = (const float*)d_in[0];
    const int*   ei     = (const int*)d_in[1];
    const int*   batch  = (const int*)d_in[2];
    const float* Wn     = (const float*)d_in[3];
    const float* Ws     = (const float*)d_in[4];
    const float* bias   = (const float*)d_in[5];
    const float* W1     = (const float*)d_in[6];
    const float* b1     = (const float*)d_in[7];
    const float* W2     = (const float*)d_in[8];
    const float* b2     = (const float*)d_in[9];

    float* out = (float*)d_out;
    int n_edges = in_sizes[1] / 2;
    const int* src = ei;
    const int* dst = ei + n_edges;
    int stripe = (n_edges + S_STRIPES - 1) / S_STRIPES;

    // ws (ints): deg_i[N] | off[N+1] | bsums[64] | start[G+1] | pad[2] |
    //            xh[N*32] | adj[E(pad4)] | agg[N*32] | h[S*N] | p[S*N]
    // (~42 MB; ws_size ~268 MB per harness fill)
    int* deg_i   = (int*)d_ws;
    int* off     = deg_i + N_NODES_C;
    int* bsums   = off + (N_NODES_C + 1);
    int* start   = bsums + 64;
    unsigned* xh = (unsigned*)(start + (N_GRAPHS_C + 1) + 2);   // 16B-aligned
    int* adj     = (int*)(xh + (size_t)N_NODES_C * 32);
    unsigned* agg = (unsigned*)(adj + ((n_edges + 3) & ~3));
    int* h       = (int*)(agg + (size_t)N_NODES_C * 32);
    int* p       = h + (size_t)S_STRIPES * N_NODES_C;

    prep_kernel<<<1024, 256, 0, stream>>>(x, batch, xh, start);
    hist2d_kernel<<<S_STRIPES * N_RANGES, 1024, 0, stream>>>(dst, h, n_edges, stripe);
    reduce_kernel<<<(N_NODES_C + 255) / 256, 256, 0, stream>>>(h, p, deg_i);
    scan1_kernel<<<N_SCAN_BLK, 256, 0, stream>>>(deg_i, bsums, N_NODES_C);
    scan3_kernel<<<N_SCAN_BLK, 256, 0, stream>>>(deg_i, bsums, off, N_NODES_C);
    scatter2d_kernel<<<S_STRIPES * N_RANGES, 1024, 0, stream>>>(src, dst, off, p,
                                                                adj, n_edges, stripe);

    gather_mean_kernel<<<12500, 256, 0, stream>>>(xh, adj, off, agg);

    gemm_kernel<<<782, 256, 0, stream>>>(xh, agg, Wn, Ws, bias, out);

    poolhead_kernel<<<N_GRAPHS_C, 256, 0, stream>>>(out, start, W1, b1, W2, b2,
                                                    out + (size_t)N_NODES_C * HID_C);
}